// Round 9
// baseline (460.853 us; speedup 1.0000x reference)
//
#include <hip/hip_runtime.h>

#define H      128
#define OBSROW 141
#define GPB    16     // graphs per block (MFMA M dimension)
#define NT     512    // 8 waves = 8 o-tiles; each wave owns all 13 nodes

typedef __bf16 bf16x8 __attribute__((ext_vector_type(8)));
typedef float  f32x4  __attribute__((ext_vector_type(4)));

__device__ __forceinline__ float eluf(float v) {
    return v > 0.0f ? v : (__expf(v) - 1.0f);
}
__device__ __forceinline__ unsigned int pk2(float a, float b) {
    const unsigned short lo = __builtin_bit_cast(unsigned short, (__bf16)a);
    const unsigned short hi = __builtin_bit_cast(unsigned short, (__bf16)b);
    return (unsigned)lo | ((unsigned)hi << 16);
}
__device__ __forceinline__ float upk(unsigned int p, int e) {
    return (float)__builtin_bit_cast(__bf16, (unsigned short)(e ? (p >> 16) : p));
}
__device__ __forceinline__ f32x4 yv(const unsigned int* p) {
    f32x4 r; r[0] = upk(p[0],0); r[1] = upk(p[0],1); r[2] = upk(p[1],0); r[3] = upk(p[1],1);
    return r;
}

// ws (bf16 elems): [0)Wrel 3*16384 | [49152)Wroot 3*16384 | [98304)We_b pad[128][64] | [106496)We_j pad[128][32]
#define WS_ROOT 49152
#define WS_EB   98304
#define WS_EJ   106496
#define WS_TOT  110592

__global__ void convert_weights(const float* __restrict__ Wr, const float* __restrict__ Wo,
                                const float* __restrict__ Web, const float* __restrict__ Wej,
                                __bf16* __restrict__ ws) {
    const int i = blockIdx.x * 256 + threadIdx.x;
    if (i < WS_ROOT) {
        ws[i] = (__bf16)Wr[i];
    } else if (i < WS_EB) {
        ws[i] = (__bf16)Wo[i - WS_ROOT];
    } else if (i < WS_EJ) {
        const int j = i - WS_EB, o = j >> 6, f = j & 63;
        ws[i] = (__bf16)(f < 33 ? Web[o*33 + f] : 0.0f);
    } else if (i < WS_TOT) {
        const int j = i - WS_EJ, o = j >> 5, f = j & 31;
        ws[i] = (__bf16)(f < 9 ? Wej[o*9 + f] : 0.0f);
    }
}

// X layout: [node 13][hc=h/8 16][graph 16][hi 8]  (bf16) -> A-frag = 16B contiguous
#define XIDX(n,hc,g,hi) (((((n)*16 + (hc))*16 + (g))*8) + (hi))

__launch_bounds__(NT, 4)   // 4 waves/EU -> 128-reg cap; 2 blocks/CU (LDS 67.6 KB)
__global__ void gnn_fused(const float* __restrict__ obs,
                          const float* __restrict__ be_b, const float* __restrict__ be_j,
                          const float* __restrict__ b_rel,
                          const float* __restrict__ W_dec, const float* __restrict__ b_dec,
                          const __bf16* __restrict__ wsb,
                          float* __restrict__ out, int B)
{
    __shared__ __align__(16) unsigned short Xs[13*2048];   // 53248 B (single buffer)
    __shared__ __align__(16) unsigned short Fs[7168];      // 14336 B obs staging

    const int tid  = threadIdx.x;
    const int wave = tid >> 6;     // 0..7 == o-tile
    const int lane = tid & 63;
    const int q    = lane >> 4;    // quad 0..3
    const int c    = lane & 15;    // col-in-tile / graph-in-chunk
    const int g0   = blockIdx.x * GPB;
    const int jt   = wave;
    const int o    = jt*16 + c;

    // in-edge adjacency of the fixed 24-edge tree (both directions folded in)
    static constexpr int INDEG[13]    = {4,2,2,1,2,2,1,2,2,1,2,2,1};
    static constexpr int INSRC[13][4] = {
        {1,4,7,10},{0,2,0,0},{1,3,0,0},{2,0,0,0},{0,5,0,0},{4,6,0,0},{5,0,0,0},
        {0,8,0,0},{7,9,0,0},{8,0,0,0},{0,11,0,0},{10,12,0,0},{11,0,0,0}};

    // ---------------- stage obs features ----------------
    // joints at Fs[jj*512 + fc*128 + g*8 + hi] (jj 0..11, f = fc*8+hi, f<9 valid)
    for (int s = tid; s < 6144; s += NT) {
        const int jj = s >> 9, rem = s & 511;
        const int fc = rem >> 7, g = (rem >> 3) & 15, hi = rem & 7;
        const int f = fc*8 + hi;
        float v = 0.0f;
        if (f < 9 && (g0 + g) < B)
            v = obs[(g0+g)*OBSROW + (f/3)*47 + 9 + (f%3)*12 + jj];
        *(__bf16*)&Fs[s] = (__bf16)v;
    }
    // base at Fs[6144 + fc*128 + g*8 + hi] (f = fc*8+hi, f<33 valid, K padded to 64)
    for (int s = tid; s < 1024; s += NT) {
        const int fc = s >> 7, rem = s & 127, g = rem >> 3, hi = rem & 7;
        const int f = fc*8 + hi;
        float v = 0.0f;
        if (f < 33 && (g0 + g) < B) {
            const int tt = f / 11, i2 = f % 11;   // BASE_IDX[i] = i<9 ? i : 36+i
            v = obs[(g0+g)*OBSROW + tt*47 + (i2 < 9 ? i2 : 36 + i2)];
        }
        *(__bf16*)&Fs[6144 + s] = (__bf16)v;
    }
    __syncthreads();

    // ---------------- encoders (each wave: full 13 nodes for its o-tile) ----------------
    {   // node 0 (base), K=64 -> 2 MFMAs
        const bf16x8 u0 = *(const bf16x8*)(wsb + WS_EB + o*64 + q*8);
        const bf16x8 u1 = *(const bf16x8*)(wsb + WS_EB + o*64 + 32 + q*8);
        const bf16x8 a0 = *(const bf16x8*)&Fs[6144 + q*128 + c*8];
        const bf16x8 a1 = *(const bf16x8*)&Fs[6144 + 512 + q*128 + c*8];
        f32x4 acc = {0.f,0.f,0.f,0.f};
        acc = __builtin_amdgcn_mfma_f32_16x16x32_bf16(a0, u0, acc, 0,0,0);
        acc = __builtin_amdgcn_mfma_f32_16x16x32_bf16(a1, u1, acc, 0,0,0);
        const float bias = be_b[o];
        #pragma unroll
        for (int r = 0; r < 4; r++)
            *(__bf16*)&Xs[XIDX(0, jt*2 + (c>>3), q*4 + r, c & 7)] = (__bf16)eluf(acc[r] + bias);
    }
    {   // joints 0..11, K=32 -> 1 MFMA each
        const bf16x8 uj = *(const bf16x8*)(wsb + WS_EJ + o*32 + q*8);
        const float bias = be_j[o];
        #pragma unroll
        for (int jj = 0; jj < 12; jj++) {
            const bf16x8 a = *(const bf16x8*)&Fs[jj*512 + q*128 + c*8];
            f32x4 acc = {0.f,0.f,0.f,0.f};
            acc = __builtin_amdgcn_mfma_f32_16x16x32_bf16(a, uj, acc, 0,0,0);
            #pragma unroll
            for (int r = 0; r < 4; r++)
                *(__bf16*)&Xs[XIDX(1+jj, jt*2 + (c>>3), q*4 + r, c & 7)] = (__bf16)eluf(acc[r] + bias);
        }
    }
    __syncthreads();

    // ---------------- 3 GraphConv layers (2 barriers each; scatter-add in-register) ----------------
    const unsigned short* xr = Xs + q*128 + c*8;   // A-frag(n,k) at xr + n*2048 + k*512
    #pragma unroll 1
    for (int l = 0; l < 3; l++) {
        unsigned int ypk[13][2], cpk[13][2];   // packed bf16 Yrel / Yroot tiles
        {
            bf16x8 brel[4], broot[4];
            #pragma unroll
            for (int k = 0; k < 4; k++) {
                brel[k]  = *(const bf16x8*)(wsb + l*16384 + o*128 + k*32 + q*8);
                broot[k] = *(const bf16x8*)(wsb + WS_ROOT + l*16384 + o*128 + k*32 + q*8);
            }
            // one A-read feeds BOTH chains: 4 ds_read_b128 -> 8 MFMAs per node
            #pragma unroll
            for (int n = 0; n < 13; n++) {
                f32x4 y = {0.f,0.f,0.f,0.f}, r = {0.f,0.f,0.f,0.f};
                #pragma unroll
                for (int k = 0; k < 4; k++) {
                    const bf16x8 xa = *(const bf16x8*)(xr + n*2048 + k*512);
                    y = __builtin_amdgcn_mfma_f32_16x16x32_bf16(xa, brel[k],  y, 0,0,0);
                    r = __builtin_amdgcn_mfma_f32_16x16x32_bf16(xa, broot[k], r, 0,0,0);
                }
                ypk[n][0] = pk2(y[0], y[1]); ypk[n][1] = pk2(y[2], y[3]);
                cpk[n][0] = pk2(r[0], r[1]); cpk[n][1] = pk2(r[2], r[3]);
            }
        }
        // scatter-add entirely in registers
        const float bias = b_rel[l*H + o];
        unsigned int stash[13][2];
        #pragma unroll
        for (int n = 0; n < 13; n++) {
            f32x4 acc = yv(cpk[n]);
            #pragma unroll
            for (int e = 0; e < 4; e++)
                if (e < INDEG[n]) acc += yv(ypk[INSRC[n][e]]);
            stash[n][0] = pk2(eluf(acc[0]+bias), eluf(acc[1]+bias));
            stash[n][1] = pk2(eluf(acc[2]+bias), eluf(acc[3]+bias));
        }
        __syncthreads();   // all X reads done
        {
            const int hc = jt*2 + (c >> 3);
            const int hi = c & 7;
            #pragma unroll
            for (int n = 0; n < 13; n++) {
                Xs[XIDX(n, hc, q*4+0, hi)] = (unsigned short)(stash[n][0]);
                Xs[XIDX(n, hc, q*4+1, hi)] = (unsigned short)(stash[n][0] >> 16);
                Xs[XIDX(n, hc, q*4+2, hi)] = (unsigned short)(stash[n][1]);
                Xs[XIDX(n, hc, q*4+3, hi)] = (unsigned short)(stash[n][1] >> 16);
            }
        }
        __syncthreads();   // new X visible
    }

    // ---------------- decoder: out[g][j] = x[j+1]·W_dec + b_dec ----------------
    {
        // decoder base: hc = q*4 + hq  ->  h = q*32 + hq*8 + hi (matches wd indexing)
        const unsigned short* xdec = Xs + q*512 + c*8;
        float wd[32];
        #pragma unroll
        for (int i4 = 0; i4 < 8; i4++) {
            const float4 wv = *(const float4*)&W_dec[q*32 + i4*4];
            wd[i4*4+0] = wv.x; wd[i4*4+1] = wv.y; wd[i4*4+2] = wv.z; wd[i4*4+3] = wv.w;
        }
        const float bd = b_dec[0];
        for (int j = wave; j < 12; j += 8) {    // waves 0..3 do two joints, 4..7 one
            float s = 0.0f;
            #pragma unroll
            for (int hq = 0; hq < 4; hq++) {    // lane covers h = q*32 + hq*8 + hi
                const bf16x8 xv = *(const bf16x8*)(xdec + (j+1)*2048 + hq*128);
                #pragma unroll
                for (int hi2 = 0; hi2 < 8; hi2++)
                    s += (float)xv[hi2] * wd[hq*8 + hi2];
            }
            s += __shfl_xor(s, 16);
            s += __shfl_xor(s, 32);
            if (q == 0 && (g0 + c) < B)
                out[(g0 + c)*12 + j] = s + bd;
        }
    }
}

extern "C" void kernel_launch(void* const* d_in, const int* in_sizes, int n_in,
                              void* d_out, int out_size, void* d_ws, size_t ws_size,
                              hipStream_t stream) {
    const float* obs   = (const float*)d_in[0];
    const float* We_b  = (const float*)d_in[1];
    const float* be_b  = (const float*)d_in[2];
    const float* We_j  = (const float*)d_in[3];
    const float* be_j  = (const float*)d_in[4];
    const float* W_rel = (const float*)d_in[5];
    const float* W_root= (const float*)d_in[6];
    const float* b_rel = (const float*)d_in[7];
    const float* W_dec = (const float*)d_in[8];
    const float* b_dec = (const float*)d_in[9];
    // d_in[10]/d_in[11] (src/dst) are the fixed tree edges; adjacency is baked in.
    float* out = (float*)d_out;
    __bf16* wsb = (__bf16*)d_ws;   // 221 KB of bf16 weights

    const int B = in_sizes[0] / OBSROW;
    convert_weights<<<(WS_TOT + 255) / 256, 256, 0, stream>>>(W_rel, W_root, We_b, We_j, wsb);
    const int blocks = (B + GPB - 1) / GPB;
    gnn_fused<<<blocks, NT, 0, stream>>>(obs, be_b, be_j, b_rel, W_dec, b_dec,
                                         wsb, out, B);
}

// Round 10
// 326.919 us; speedup vs baseline: 1.4097x; 1.4097x over previous
//
#include <hip/hip_runtime.h>

#define H      128
#define OBSROW 141
#define GPB    16     // graphs per block (MFMA M dimension)
#define NT     512    // 8 waves = 8 o-tiles; each wave owns all 13 nodes

typedef __bf16 bf16x8 __attribute__((ext_vector_type(8)));
typedef float  f32x4  __attribute__((ext_vector_type(4)));

__device__ __forceinline__ float eluf(float v) {
    return v > 0.0f ? v : (__expf(v) - 1.0f);
}
__device__ __forceinline__ f32x4 mf(bf16x8 a, bf16x8 b, f32x4 c) {
    return __builtin_amdgcn_mfma_f32_16x16x32_bf16(a, b, c, 0, 0, 0);
}

// ws (bf16 elems): [0)Wrel 3*16384 | [49152)Wroot 3*16384 | [98304)We_b pad[128][64] | [106496)We_j pad[128][32]
#define WS_ROOT 49152
#define WS_EB   98304
#define WS_EJ   106496
#define WS_TOT  110592

__global__ void convert_weights(const float* __restrict__ Wr, const float* __restrict__ Wo,
                                const float* __restrict__ Web, const float* __restrict__ Wej,
                                __bf16* __restrict__ ws) {
    const int i = blockIdx.x * 256 + threadIdx.x;
    if (i < WS_ROOT) {
        ws[i] = (__bf16)Wr[i];
    } else if (i < WS_EB) {
        ws[i] = (__bf16)Wo[i - WS_ROOT];
    } else if (i < WS_EJ) {
        const int j = i - WS_EB, o = j >> 6, f = j & 63;
        ws[i] = (__bf16)(f < 33 ? Web[o*33 + f] : 0.0f);
    } else if (i < WS_TOT) {
        const int j = i - WS_EJ, o = j >> 5, f = j & 31;
        ws[i] = (__bf16)(f < 9 ? Wej[o*9 + f] : 0.0f);
    }
}

// X layout: [node 13][hc=h/8 16][graph 16][hi 8]  (bf16) -> A-frag = 16B contiguous
#define XIDX(n,hc,g,hi) (((((n)*16 + (hc))*16 + (g))*8) + (hi))

__launch_bounds__(NT, 4)   // 4 waves/EU -> 128-reg cap; 2 blocks/CU (LDS 67.6 KB)
__global__ void gnn_fused(const float* __restrict__ obs,
                          const float* __restrict__ be_b, const float* __restrict__ be_j,
                          const float* __restrict__ b_rel,
                          const float* __restrict__ W_dec, const float* __restrict__ b_dec,
                          const __bf16* __restrict__ wsb,
                          float* __restrict__ out, int B)
{
    __shared__ __align__(16) unsigned short Xs[13*2048];   // 53248 B (single buffer)
    __shared__ __align__(16) unsigned short Fs[7168];      // 14336 B obs staging

    const int tid  = threadIdx.x;
    const int wave = tid >> 6;     // 0..7 == o-tile
    const int lane = tid & 63;
    const int q    = lane >> 4;    // quad 0..3
    const int c    = lane & 15;    // col-in-tile / graph-in-chunk
    const int g0   = blockIdx.x * GPB;
    const int jt   = wave;
    const int o    = jt*16 + c;

    // ---------------- stage obs features ----------------
    // joints at Fs[jj*512 + fc*128 + g*8 + hi] (jj 0..11, f = fc*8+hi, f<9 valid)
    for (int s = tid; s < 6144; s += NT) {
        const int jj = s >> 9, rem = s & 511;
        const int fc = rem >> 7, g = (rem >> 3) & 15, hi = rem & 7;
        const int f = fc*8 + hi;
        float v = 0.0f;
        if (f < 9 && (g0 + g) < B)
            v = obs[(g0+g)*OBSROW + (f/3)*47 + 9 + (f%3)*12 + jj];
        *(__bf16*)&Fs[s] = (__bf16)v;
    }
    // base at Fs[6144 + fc*128 + g*8 + hi] (f = fc*8+hi, f<33 valid, K padded to 64)
    for (int s = tid; s < 1024; s += NT) {
        const int fc = s >> 7, rem = s & 127, g = rem >> 3, hi = rem & 7;
        const int f = fc*8 + hi;
        float v = 0.0f;
        if (f < 33 && (g0 + g) < B) {
            const int tt = f / 11, i2 = f % 11;   // BASE_IDX[i] = i<9 ? i : 36+i
            v = obs[(g0+g)*OBSROW + tt*47 + (i2 < 9 ? i2 : 36 + i2)];
        }
        *(__bf16*)&Fs[6144 + s] = (__bf16)v;
    }
    __syncthreads();

    // ---------------- encoders (each wave: full 13 nodes for its o-tile) ----------------
    {   // node 0 (base), K=64 -> 2 MFMAs
        const bf16x8 u0 = *(const bf16x8*)(wsb + WS_EB + o*64 + q*8);
        const bf16x8 u1 = *(const bf16x8*)(wsb + WS_EB + o*64 + 32 + q*8);
        const bf16x8 a0 = *(const bf16x8*)&Fs[6144 + q*128 + c*8];
        const bf16x8 a1 = *(const bf16x8*)&Fs[6144 + 512 + q*128 + c*8];
        f32x4 acc = {0.f,0.f,0.f,0.f};
        acc = mf(a0, u0, acc);
        acc = mf(a1, u1, acc);
        const float bias = be_b[o];
        #pragma unroll
        for (int r = 0; r < 4; r++)
            *(__bf16*)&Xs[XIDX(0, jt*2 + (c>>3), q*4 + r, c & 7)] = (__bf16)eluf(acc[r] + bias);
    }
    {   // joints 0..11, K=32 -> 1 MFMA each
        const bf16x8 uj = *(const bf16x8*)(wsb + WS_EJ + o*32 + q*8);
        const float bias = be_j[o];
        #pragma unroll
        for (int jj = 0; jj < 12; jj++) {
            const bf16x8 a = *(const bf16x8*)&Fs[jj*512 + q*128 + c*8];
            f32x4 acc = {0.f,0.f,0.f,0.f};
            acc = mf(a, uj, acc);
            #pragma unroll
            for (int r = 0; r < 4; r++)
                *(__bf16*)&Xs[XIDX(1+jj, jt*2 + (c>>3), q*4 + r, c & 7)] = (__bf16)eluf(acc[r] + bias);
        }
    }
    __syncthreads();

    // ---------------- 3 GraphConv layers ----------------
    // Phase-sequenced f32 accumulators (AGPR-resident), peak ~80 acc regs:
    //   P1: nodes 0..6 (y+r)  -> P2a: nodes 7,10 -> scatterA -> P2b: 8,9,11,12 -> scatterB
    const unsigned short* xr = Xs + q*128 + c*8;   // A-frag(n,k) at xr + n*2048 + k*512
    #pragma unroll 1
    for (int l = 0; l < 3; l++) {
        const __bf16* wr = wsb + l*16384 + o*128 + q*8;
        const __bf16* wo = wsb + WS_ROOT + l*16384 + o*128 + q*8;

        // ---- phase 1: nodes 0..6, fused rel+root chains (one A-read, two MFMAs)
        f32x4 y1[7], r1[7];
        #pragma unroll
        for (int i = 0; i < 7; i++) {
            y1[i] = (f32x4){0.f,0.f,0.f,0.f};
            r1[i] = (f32x4){0.f,0.f,0.f,0.f};
        }
        #pragma unroll
        for (int k = 0; k < 4; k++) {
            const bf16x8 br = *(const bf16x8*)(wr + k*32);
            const bf16x8 bo = *(const bf16x8*)(wo + k*32);
            #pragma unroll
            for (int n = 0; n < 7; n++) {
                const bf16x8 xa = *(const bf16x8*)(xr + n*2048 + k*512);
                y1[n] = mf(xa, br, y1[n]);
                r1[n] = mf(xa, bo, r1[n]);
            }
        }
        // ---- phase 2a: nodes 7, 10
        f32x4 y7  = {0.f,0.f,0.f,0.f}, r7  = {0.f,0.f,0.f,0.f};
        f32x4 y10 = {0.f,0.f,0.f,0.f}, r10 = {0.f,0.f,0.f,0.f};
        #pragma unroll
        for (int k = 0; k < 4; k++) {
            const bf16x8 br = *(const bf16x8*)(wr + k*32);
            const bf16x8 bo = *(const bf16x8*)(wo + k*32);
            const bf16x8 xa7  = *(const bf16x8*)(xr + 7*2048  + k*512);
            const bf16x8 xa10 = *(const bf16x8*)(xr + 10*2048 + k*512);
            y7  = mf(xa7,  br, y7);  r7  = mf(xa7,  bo, r7);
            y10 = mf(xa10, br, y10); r10 = mf(xa10, bo, r10);
        }
        // ---- scatter A (in-edge sums for nodes 0..6); frees y1[1..6]
        r1[0] += y1[1] + y1[4] + y7 + y10;
        r1[1] += y1[0] + y1[2];
        r1[2] += y1[1] + y1[3];
        r1[3] += y1[2];
        r1[4] += y1[0] + y1[5];
        r1[5] += y1[4] + y1[6];
        r1[6] += y1[5];
        const f32x4 y0 = y1[0];
        // ---- phase 2b: nodes 8, 9, 11, 12
        f32x4 yb[4], rb[4];
        #pragma unroll
        for (int i = 0; i < 4; i++) {
            yb[i] = (f32x4){0.f,0.f,0.f,0.f};
            rb[i] = (f32x4){0.f,0.f,0.f,0.f};
        }
        static constexpr int N2B[4] = {8, 9, 11, 12};
        #pragma unroll
        for (int k = 0; k < 4; k++) {
            const bf16x8 br = *(const bf16x8*)(wr + k*32);
            const bf16x8 bo = *(const bf16x8*)(wo + k*32);
            #pragma unroll
            for (int i = 0; i < 4; i++) {
                const bf16x8 xa = *(const bf16x8*)(xr + N2B[i]*2048 + k*512);
                yb[i] = mf(xa, br, yb[i]);
                rb[i] = mf(xa, bo, rb[i]);
            }
        }
        // ---- scatter B (nodes 7..12)
        r7    += y0 + yb[0];        // node 7  <- {0,8}
        rb[0] += y7 + yb[1];        // node 8  <- {7,9}
        rb[1] += yb[0];             // node 9  <- {8}
        r10   += y0 + yb[2];        // node 10 <- {0,11}
        rb[2] += y10 + yb[3];       // node 11 <- {10,12}
        rb[3] += yb[2];             // node 12 <- {11}
        __syncthreads();   // all X reads done
        // ---- epilogue: bias + elu + cvt, write new X in place
        {
            const float bias = b_rel[l*H + o];
            const int hc = jt*2 + (c >> 3);
            const int hi = c & 7;
            #define WOUT(n, res)                                                          \
                { _Pragma("unroll")                                                       \
                  for (int r = 0; r < 4; r++)                                             \
                      *(__bf16*)&Xs[XIDX(n, hc, q*4 + r, hi)] = (__bf16)eluf((res)[r] + bias); }
            WOUT(0, r1[0]); WOUT(1, r1[1]); WOUT(2, r1[2]); WOUT(3, r1[3]);
            WOUT(4, r1[4]); WOUT(5, r1[5]); WOUT(6, r1[6]);
            WOUT(7, r7);    WOUT(8, rb[0]); WOUT(9, rb[1]);
            WOUT(10, r10);  WOUT(11, rb[2]); WOUT(12, rb[3]);
            #undef WOUT
        }
        __syncthreads();   // new X visible
    }

    // ---------------- decoder: out[g][j] = x[j+1]·W_dec + b_dec ----------------
    {
        // decoder base: hc = q*4 + hq  ->  h = q*32 + hq*8 + hi (matches wd indexing)
        const unsigned short* xdec = Xs + q*512 + c*8;
        float wd[32];
        #pragma unroll
        for (int i4 = 0; i4 < 8; i4++) {
            const float4 wv = *(const float4*)&W_dec[q*32 + i4*4];
            wd[i4*4+0] = wv.x; wd[i4*4+1] = wv.y; wd[i4*4+2] = wv.z; wd[i4*4+3] = wv.w;
        }
        const float bd = b_dec[0];
        for (int j = wave; j < 12; j += 8) {    // waves 0..3 do two joints, 4..7 one
            float s = 0.0f;
            #pragma unroll
            for (int hq = 0; hq < 4; hq++) {    // lane covers h = q*32 + hq*8 + hi
                const bf16x8 xv = *(const bf16x8*)(xdec + (j+1)*2048 + hq*128);
                #pragma unroll
                for (int hi2 = 0; hi2 < 8; hi2++)
                    s += (float)xv[hi2] * wd[hq*8 + hi2];
            }
            s += __shfl_xor(s, 16);
            s += __shfl_xor(s, 32);
            if (q == 0 && (g0 + c) < B)
                out[(g0 + c)*12 + j] = s + bd;
        }
    }
}

extern "C" void kernel_launch(void* const* d_in, const int* in_sizes, int n_in,
                              void* d_out, int out_size, void* d_ws, size_t ws_size,
                              hipStream_t stream) {
    const float* obs   = (const float*)d_in[0];
    const float* We_b  = (const float*)d_in[1];
    const float* be_b  = (const float*)d_in[2];
    const float* We_j  = (const float*)d_in[3];
    const float* be_j  = (const float*)d_in[4];
    const float* W_rel = (const float*)d_in[5];
    const float* W_root= (const float*)d_in[6];
    const float* b_rel = (const float*)d_in[7];
    const float* W_dec = (const float*)d_in[8];
    const float* b_dec = (const float*)d_in[9];
    // d_in[10]/d_in[11] (src/dst) are the fixed tree edges; adjacency is baked in.
    float* out = (float*)d_out;
    __bf16* wsb = (__bf16*)d_ws;   // 221 KB of bf16 weights

    const int B = in_sizes[0] / OBSROW;
    convert_weights<<<(WS_TOT + 255) / 256, 256, 0, stream>>>(W_rel, W_root, We_b, We_j, wsb);
    const int blocks = (B + GPB - 1) / GPB;
    gnn_fused<<<blocks, NT, 0, stream>>>(obs, be_b, be_j, b_rel, W_dec, b_dec,
                                         wsb, out, B);
}

// Round 11
// 204.714 us; speedup vs baseline: 2.2512x; 1.5970x over previous
//
#include <hip/hip_runtime.h>

#define H      128
#define OBSROW 141
#define GPB    16     // graphs per block (MFMA M dimension)
#define NT     512    // 8 waves = 8 o-tiles; each wave owns all 13 nodes

typedef __bf16 bf16x8 __attribute__((ext_vector_type(8)));
typedef float  f32x4  __attribute__((ext_vector_type(4)));

__device__ __forceinline__ float eluf(float v) {
    return v > 0.0f ? v : (__expf(v) - 1.0f);
}
__device__ __forceinline__ f32x4 mf(bf16x8 a, bf16x8 b, f32x4 c) {
    return __builtin_amdgcn_mfma_f32_16x16x32_bf16(a, b, c, 0, 0, 0);
}

// ws (bf16 elems): [0)Wrel 3*16384 | [49152)Wroot 3*16384 | [98304)We_b pad[128][64] | [106496)We_j pad[128][32]
#define WS_ROOT 49152
#define WS_EB   98304
#define WS_EJ   106496
#define WS_TOT  110592

__global__ void convert_weights(const float* __restrict__ Wr, const float* __restrict__ Wo,
                                const float* __restrict__ Web, const float* __restrict__ Wej,
                                __bf16* __restrict__ ws) {
    const int i = blockIdx.x * 256 + threadIdx.x;
    if (i < WS_ROOT) {
        ws[i] = (__bf16)Wr[i];
    } else if (i < WS_EB) {
        ws[i] = (__bf16)Wo[i - WS_ROOT];
    } else if (i < WS_EJ) {
        const int j = i - WS_EB, o = j >> 6, f = j & 63;
        ws[i] = (__bf16)(f < 33 ? Web[o*33 + f] : 0.0f);
    } else if (i < WS_TOT) {
        const int j = i - WS_EJ, o = j >> 5, f = j & 31;
        ws[i] = (__bf16)(f < 9 ? Wej[o*9 + f] : 0.0f);
    }
}

// X layout: [node 13][hc=h/8 16][graph 16][hi 8]  (bf16) -> A-frag = 16B contiguous
#define XIDX(n,hc,g,hi) (((((n)*16 + (hc))*16 + (g))*8) + (hi))

__launch_bounds__(NT, 4)   // 4 waves/EU -> 128-reg cap; peak demand ~108; 2 blocks/CU
__global__ void gnn_fused(const float* __restrict__ obs,
                          const float* __restrict__ be_b, const float* __restrict__ be_j,
                          const float* __restrict__ b_rel,
                          const float* __restrict__ W_dec, const float* __restrict__ b_dec,
                          const __bf16* __restrict__ wsb,
                          float* __restrict__ out, int B)
{
    __shared__ __align__(16) unsigned short Xs[13*2048];   // 53248 B (single buffer)
    __shared__ __align__(16) unsigned short Fs[7168];      // 14336 B obs staging

    const int tid  = threadIdx.x;
    const int wave = tid >> 6;     // 0..7 == o-tile
    const int lane = tid & 63;
    const int q    = lane >> 4;    // quad 0..3
    const int c    = lane & 15;    // col-in-tile / graph-in-chunk
    const int g0   = blockIdx.x * GPB;
    const int jt   = wave;
    const int o    = jt*16 + c;

    // out-neighbor adjacency of the undirected tree (scatter targets)
    static constexpr int ODEG[13]    = {4,2,2,1,2,2,1,2,2,1,2,2,1};
    static constexpr int ODST[13][4] = {
        {1,4,7,10},{0,2,0,0},{1,3,0,0},{2,0,0,0},{0,5,0,0},{4,6,0,0},{5,0,0,0},
        {0,8,0,0},{7,9,0,0},{8,0,0,0},{0,11,0,0},{10,12,0,0},{11,0,0,0}};

    // ---------------- stage obs features ----------------
    // joints at Fs[jj*512 + fc*128 + g*8 + hi] (jj 0..11, f = fc*8+hi, f<9 valid)
    for (int s = tid; s < 6144; s += NT) {
        const int jj = s >> 9, rem = s & 511;
        const int fc = rem >> 7, g = (rem >> 3) & 15, hi = rem & 7;
        const int f = fc*8 + hi;
        float v = 0.0f;
        if (f < 9 && (g0 + g) < B)
            v = obs[(g0+g)*OBSROW + (f/3)*47 + 9 + (f%3)*12 + jj];
        *(__bf16*)&Fs[s] = (__bf16)v;
    }
    // base at Fs[6144 + fc*128 + g*8 + hi] (f = fc*8+hi, f<33 valid, K padded to 64)
    for (int s = tid; s < 1024; s += NT) {
        const int fc = s >> 7, rem = s & 127, g = rem >> 3, hi = rem & 7;
        const int f = fc*8 + hi;
        float v = 0.0f;
        if (f < 33 && (g0 + g) < B) {
            const int tt = f / 11, i2 = f % 11;   // BASE_IDX[i] = i<9 ? i : 36+i
            v = obs[(g0+g)*OBSROW + tt*47 + (i2 < 9 ? i2 : 36 + i2)];
        }
        *(__bf16*)&Fs[6144 + s] = (__bf16)v;
    }
    __syncthreads();

    // ---------------- encoders (each wave: full 13 nodes for its o-tile) ----------------
    {   // node 0 (base), K=64 -> 2 MFMAs
        const bf16x8 u0 = *(const bf16x8*)(wsb + WS_EB + o*64 + q*8);
        const bf16x8 u1 = *(const bf16x8*)(wsb + WS_EB + o*64 + 32 + q*8);
        const bf16x8 a0 = *(const bf16x8*)&Fs[6144 + q*128 + c*8];
        const bf16x8 a1 = *(const bf16x8*)&Fs[6144 + 512 + q*128 + c*8];
        f32x4 acc = {0.f,0.f,0.f,0.f};
        acc = mf(a0, u0, acc);
        acc = mf(a1, u1, acc);
        const float bias = be_b[o];
        #pragma unroll
        for (int r = 0; r < 4; r++)
            *(__bf16*)&Xs[XIDX(0, jt*2 + (c>>3), q*4 + r, c & 7)] = (__bf16)eluf(acc[r] + bias);
    }
    {   // joints 0..11, K=32 -> 1 MFMA each
        const bf16x8 uj = *(const bf16x8*)(wsb + WS_EJ + o*32 + q*8);
        const float bias = be_j[o];
        #pragma unroll
        for (int jj = 0; jj < 12; jj++) {
            const bf16x8 a = *(const bf16x8*)&Fs[jj*512 + q*128 + c*8];
            f32x4 acc = {0.f,0.f,0.f,0.f};
            acc = mf(a, uj, acc);
            #pragma unroll
            for (int r = 0; r < 4; r++)
                *(__bf16*)&Xs[XIDX(1+jj, jt*2 + (c>>3), q*4 + r, c & 7)] = (__bf16)eluf(acc[r] + bias);
        }
    }
    __syncthreads();

    // ---------------- 3 GraphConv layers ----------------
    // Streaming scatter: acc[13] persists; per node y is transient and scattered
    // immediately. K split in halves (h-loop NOT unrolled) so only 4 B-frags live.
    // Peak regs ~ 52(acc) + 4(y) + 32(bw) + 4(xa) + ~16 addr = ~108 < 128.
    const unsigned short* xr = Xs + q*128 + c*8;   // A-frag(n,k) at xr + n*2048 + k*512
    #pragma unroll 1
    for (int l = 0; l < 3; l++) {
        const __bf16* wr = wsb + l*16384 + o*128 + q*8;
        const __bf16* wo = wsb + WS_ROOT + l*16384 + o*128 + q*8;

        f32x4 acc[13];
        #pragma unroll
        for (int n = 0; n < 13; n++) acc[n] = (f32x4){0.f,0.f,0.f,0.f};

        #pragma unroll 1
        for (int h = 0; h < 2; h++) {
            const bf16x8 br0 = *(const bf16x8*)(wr + (2*h+0)*32);
            const bf16x8 br1 = *(const bf16x8*)(wr + (2*h+1)*32);
            const bf16x8 bo0 = *(const bf16x8*)(wo + (2*h+0)*32);
            const bf16x8 bo1 = *(const bf16x8*)(wo + (2*h+1)*32);
            const unsigned short* xh = xr + 2*h*512;
            #pragma unroll
            for (int n = 0; n < 13; n++) {
                const bf16x8 xa0 = *(const bf16x8*)(xh + n*2048);
                const bf16x8 xa1 = *(const bf16x8*)(xh + n*2048 + 512);
                // root contribution straight into acc[n]
                acc[n] = mf(xa0, bo0, acc[n]);
                acc[n] = mf(xa1, bo1, acc[n]);
                // rel contribution into transient y, then scatter to neighbors
                f32x4 y = {0.f,0.f,0.f,0.f};
                y = mf(xa0, br0, y);
                y = mf(xa1, br1, y);
                #pragma unroll
                for (int e = 0; e < 4; e++)
                    if (e < ODEG[n]) acc[ODST[n][e]] += y;
            }
        }
        __syncthreads();   // all X reads done
        // ---- epilogue: bias + elu + cvt, write new X in place
        {
            const float bias = b_rel[l*H + o];
            const int hc = jt*2 + (c >> 3);
            const int hi = c & 7;
            #pragma unroll
            for (int n = 0; n < 13; n++) {
                #pragma unroll
                for (int r = 0; r < 4; r++)
                    *(__bf16*)&Xs[XIDX(n, hc, q*4 + r, hi)] = (__bf16)eluf(acc[n][r] + bias);
            }
        }
        __syncthreads();   // new X visible
    }

    // ---------------- decoder: out[g][j] = x[j+1]·W_dec + b_dec ----------------
    {
        // decoder base: hc = q*4 + hq  ->  h = q*32 + hq*8 + hi (matches wd indexing)
        const unsigned short* xdec = Xs + q*512 + c*8;
        float wd[32];
        #pragma unroll
        for (int i4 = 0; i4 < 8; i4++) {
            const float4 wv = *(const float4*)&W_dec[q*32 + i4*4];
            wd[i4*4+0] = wv.x; wd[i4*4+1] = wv.y; wd[i4*4+2] = wv.z; wd[i4*4+3] = wv.w;
        }
        const float bd = b_dec[0];
        for (int j = wave; j < 12; j += 8) {    // waves 0..3 do two joints, 4..7 one
            float s = 0.0f;
            #pragma unroll
            for (int hq = 0; hq < 4; hq++) {    // lane covers h = q*32 + hq*8 + hi
                const bf16x8 xv = *(const bf16x8*)(xdec + (j+1)*2048 + hq*128);
                #pragma unroll
                for (int hi2 = 0; hi2 < 8; hi2++)
                    s += (float)xv[hi2] * wd[hq*8 + hi2];
            }
            s += __shfl_xor(s, 16);
            s += __shfl_xor(s, 32);
            if (q == 0 && (g0 + c) < B)
                out[(g0 + c)*12 + j] = s + bd;
        }
    }
}

extern "C" void kernel_launch(void* const* d_in, const int* in_sizes, int n_in,
                              void* d_out, int out_size, void* d_ws, size_t ws_size,
                              hipStream_t stream) {
    const float* obs   = (const float*)d_in[0];
    const float* We_b  = (const float*)d_in[1];
    const float* be_b  = (const float*)d_in[2];
    const float* We_j  = (const float*)d_in[3];
    const float* be_j  = (const float*)d_in[4];
    const float* W_rel = (const float*)d_in[5];
    const float* W_root= (const float*)d_in[6];
    const float* b_rel = (const float*)d_in[7];
    const float* W_dec = (const float*)d_in[8];
    const float* b_dec = (const float*)d_in[9];
    // d_in[10]/d_in[11] (src/dst) are the fixed tree edges; adjacency is baked in.
    float* out = (float*)d_out;
    __bf16* wsb = (__bf16*)d_ws;   // 221 KB of bf16 weights

    const int B = in_sizes[0] / OBSROW;
    convert_weights<<<(WS_TOT + 255) / 256, 256, 0, stream>>>(W_rel, W_root, We_b, We_j, wsb);
    const int blocks = (B + GPB - 1) / GPB;
    gnn_fused<<<blocks, NT, 0, stream>>>(obs, be_b, be_j, b_rel, W_dec, b_dec,
                                         wsb, out, B);
}